// Round 1
// baseline (1944.324 us; speedup 1.0000x reference)
//
#include <hip/hip_runtime.h>
#include <hip/hip_bf16.h>

#define SS 512
#define BATCH 2048
#define GL 32
#define OL 20
#define MM 32
#define CC 16
#define GM 64
#define OM 20
#define GR 128
#define ORR 38
#define IMID 384
#define IROOT 768
#define EPSBN 1e-5f

// ---- workspace layout (floats) ----
#define SZ_CHILD ((size_t)MM * BATCH * CC * OL)   // 20,971,520
#define SZ_HM    ((size_t)MM * BATCH * OM)        // 1,310,720
#define SZ_MIDP  ((size_t)MM * 32 * 2 * OM)       // 40,960
#define SZ_MIDN  ((size_t)BATCH * MM * OM)        // 1,310,720
#define SZ_HR    ((size_t)BATCH * ORR)            // 77,824
#define OFF_HM   (SZ_CHILD)
#define OFF_MIDP (OFF_HM + SZ_HM)
#define OFF_MIDN (OFF_MIDP + SZ_MIDP)
#define OFF_HR   (OFF_MIDN + SZ_MIDN)
#define OFF_RP   (OFF_HR + SZ_HR)

#define FMA20(xs, wptr, acc) do { \
  const float4* _wr = (const float4*)(wptr); \
  float4 _w0=_wr[0], _w1=_wr[1], _w2=_wr[2], _w3=_wr[3], _w4=_wr[4]; \
  acc[0]=fmaf(xs,_w0.x,acc[0]);  acc[1]=fmaf(xs,_w0.y,acc[1]); \
  acc[2]=fmaf(xs,_w0.z,acc[2]);  acc[3]=fmaf(xs,_w0.w,acc[3]); \
  acc[4]=fmaf(xs,_w1.x,acc[4]);  acc[5]=fmaf(xs,_w1.y,acc[5]); \
  acc[6]=fmaf(xs,_w1.z,acc[6]);  acc[7]=fmaf(xs,_w1.w,acc[7]); \
  acc[8]=fmaf(xs,_w2.x,acc[8]);  acc[9]=fmaf(xs,_w2.y,acc[9]); \
  acc[10]=fmaf(xs,_w2.z,acc[10]); acc[11]=fmaf(xs,_w2.w,acc[11]); \
  acc[12]=fmaf(xs,_w3.x,acc[12]); acc[13]=fmaf(xs,_w3.y,acc[13]); \
  acc[14]=fmaf(xs,_w3.z,acc[14]); acc[15]=fmaf(xs,_w3.w,acc[15]); \
  acc[16]=fmaf(xs,_w4.x,acc[16]); acc[17]=fmaf(xs,_w4.y,acc[17]); \
  acc[18]=fmaf(xs,_w4.z,acc[18]); acc[19]=fmaf(xs,_w4.w,acc[19]); \
} while (0)

// ---------------- leaf: one block per subsystem, full-batch BN in-block ----
__global__ __launch_bounds__(512) void k_leaf(
    const float* __restrict__ x, const float* __restrict__ W,
    const float* __restrict__ bias, const float* __restrict__ g,
    const float* __restrict__ be, float* __restrict__ child)
{
  const int s = blockIdx.x;
  const int t = threadIdx.x;
  __shared__ float Wl[GL * OL];
  __shared__ float red[8][2 * OL];
  __shared__ float scsh[2 * OL];

  for (int i = t; i < GL * OL / 4; i += 512)
    ((float4*)Wl)[i] = ((const float4*)(W + (size_t)s * GL * OL))[i];
  __syncthreads();

  float h[4][OL];
  float sum[OL], ssq[OL];
#pragma unroll
  for (int o = 0; o < OL; o++) { sum[o] = 0.f; ssq[o] = 0.f; }

#pragma unroll
  for (int rr = 0; rr < 4; rr++) {
    const int b = rr * 512 + t;
    const float4* xr = (const float4*)(x + ((size_t)s * BATCH + b) * GL);
    float acc[OL];
#pragma unroll
    for (int o = 0; o < OL; o++) acc[o] = 0.f;
#pragma unroll
    for (int i4 = 0; i4 < GL / 4; i4++) {
      float4 xv = xr[i4];
      float xa[4] = {xv.x, xv.y, xv.z, xv.w};
#pragma unroll
      for (int j = 0; j < 4; j++) {
        FMA20(xa[j], &Wl[(i4 * 4 + j) * OL], acc);
      }
    }
#pragma unroll
    for (int o = 0; o < OL; o++) {
      float hv = tanhf(acc[o] + bias[s * OL + o]);
      h[rr][o] = hv;
      sum[o] += hv;
      ssq[o] = fmaf(hv, hv, ssq[o]);
    }
  }

  const int wave = t >> 6, lane = t & 63;
#pragma unroll
  for (int o = 0; o < OL; o++) {
    float s1 = sum[o], s2 = ssq[o];
#pragma unroll
    for (int d = 32; d >= 1; d >>= 1) { s1 += __shfl_xor(s1, d); s2 += __shfl_xor(s2, d); }
    if (lane == 0) { red[wave][o] = s1; red[wave][OL + o] = s2; }
  }
  __syncthreads();
  if (t < 2 * OL) {
    float v = 0.f;
#pragma unroll
    for (int w2 = 0; w2 < 8; w2++) v += red[w2][t];
    red[0][t] = v;
  }
  __syncthreads();
  if (t < OL) {
    float mean = red[0][t] * (1.f / BATCH);
    float var  = red[0][OL + t] * (1.f / BATCH) - mean * mean;
    float rs = rsqrtf(var + EPSBN);
    float sc = g[s * OL + t] * rs;
    scsh[t] = sc;
    scsh[OL + t] = be[s * OL + t] - mean * sc;
  }
  __syncthreads();

  const int m = s >> 4, c = s & 15;
#pragma unroll
  for (int rr = 0; rr < 4; rr++) {
    const int b = rr * 512 + t;
    float4* dst = (float4*)(child + ((size_t)m * BATCH + b) * (CC * OL) + c * OL);
#pragma unroll
    for (int q = 0; q < 5; q++) {
      float4 v;
      v.x = h[rr][q*4+0] * scsh[q*4+0] + scsh[OL + q*4+0];
      v.y = h[rr][q*4+1] * scsh[q*4+1] + scsh[OL + q*4+1];
      v.z = h[rr][q*4+2] * scsh[q*4+2] + scsh[OL + q*4+2];
      v.w = h[rr][q*4+3] * scsh[q*4+3] + scsh[OL + q*4+3];
      dst[q] = v;
    }
  }
}

// ---------------- mid GEMM + tanh + partial stats; per-wave K-split ----------
__global__ __launch_bounds__(256) void k_mid(
    const float* __restrict__ xg, const float* __restrict__ child,
    const float* __restrict__ W, const float* __restrict__ bias,
    float* __restrict__ hm, float* __restrict__ mp)
{
  const int chunk = blockIdx.x;   // 0..31 (64 rows each)
  const int m = blockIdx.y;       // 0..31
  const int t = threadIdx.x;
  const int kq = t >> 6;          // wave id: K quarter
  const int lane = t & 63;
  const int b = chunk * 64 + lane;

  __shared__ float Wl[IMID * OM];        // 30720 B
  __shared__ float cb[3][64][21];        // combine buffer (padded)

  for (int i = t; i < IMID * OM / 4; i += 256)
    ((float4*)Wl)[i] = ((const float4*)(W + (size_t)m * IMID * OM))[i];
  __syncthreads();

  float acc[OM];
#pragma unroll
  for (int o = 0; o < OM; o++) acc[o] = 0.f;

  const float* gsrc = xg + ((size_t)m * BATCH + b) * GM;
  const float* csrc = child + ((size_t)m * BATCH + b) * (CC * OL);
  const int k0 = kq * 96;

#pragma unroll 4
  for (int k4 = 0; k4 < 24; k4++) {
    const int k = k0 + k4 * 4;
    float4 xv;
    if (k < GM) xv = *(const float4*)(gsrc + k);
    else        xv = *(const float4*)(csrc + (k - GM));
    float xa[4] = {xv.x, xv.y, xv.z, xv.w};
#pragma unroll
    for (int j = 0; j < 4; j++) {
      FMA20(xa[j], &Wl[(k + j) * OM], acc);
    }
  }

  if (kq > 0) {
#pragma unroll
    for (int o = 0; o < OM; o++) cb[kq - 1][lane][o] = acc[o];
  }
  __syncthreads();

  if (kq == 0) {
#pragma unroll
    for (int o = 0; o < OM; o++) {
      float v = acc[o] + cb[0][lane][o] + cb[1][lane][o] + cb[2][lane][o] + bias[m * OM + o];
      acc[o] = tanhf(v);
    }
    float4* dst = (float4*)(hm + ((size_t)m * BATCH + b) * OM);
#pragma unroll
    for (int q = 0; q < 5; q++) {
      float4 v; v.x = acc[q*4]; v.y = acc[q*4+1]; v.z = acc[q*4+2]; v.w = acc[q*4+3];
      dst[q] = v;
    }
#pragma unroll
    for (int o = 0; o < OM; o++) {
      float s1 = acc[o], s2 = acc[o] * acc[o];
#pragma unroll
      for (int d = 32; d >= 1; d >>= 1) { s1 += __shfl_xor(s1, d); s2 += __shfl_xor(s2, d); }
      if (lane == 0) {
        mp[((size_t)m * 32 + chunk) * (2 * OM) + o] = s1;
        mp[((size_t)m * 32 + chunk) * (2 * OM) + OM + o] = s2;
      }
    }
  }
}

// ---------------- mid BN finalize + transpose into root-input layout --------
__global__ __launch_bounds__(256) void k_midnorm(
    const float* __restrict__ hm, const float* __restrict__ mp,
    const float* __restrict__ g, const float* __restrict__ be,
    float* __restrict__ mn)
{
  const int chunk = blockIdx.x;  // 0..7 (256 rows each)
  const int m = blockIdx.y;
  const int t = threadIdx.x;
  __shared__ float sc[OM], sh[OM];
  if (t < OM) {
    float s1 = 0.f, s2 = 0.f;
    for (int c = 0; c < 32; c++) {
      s1 += mp[((size_t)m * 32 + c) * (2 * OM) + t];
      s2 += mp[((size_t)m * 32 + c) * (2 * OM) + OM + t];
    }
    float mean = s1 * (1.f / BATCH);
    float var  = s2 * (1.f / BATCH) - mean * mean;
    float r = rsqrtf(var + EPSBN);
    float scv = g[m * OM + t] * r;
    sc[t] = scv;
    sh[t] = be[m * OM + t] - mean * scv;
  }
  __syncthreads();
  const int b = chunk * 256 + t;
  const float4* src = (const float4*)(hm + ((size_t)m * BATCH + b) * OM);
  float4* dst = (float4*)(mn + (size_t)b * (MM * OM) + m * OM);
#pragma unroll
  for (int q = 0; q < 5; q++) {
    float4 v = src[q];
    v.x = v.x * sc[q*4+0] + sh[q*4+0];
    v.y = v.y * sc[q*4+1] + sh[q*4+1];
    v.z = v.z * sc[q*4+2] + sh[q*4+2];
    v.w = v.w * sc[q*4+3] + sh[q*4+3];
    dst[q] = v;
  }
}

// ---------------- root GEMM + tanh + partial stats --------------------------
__global__ __launch_bounds__(256) void k_root(
    const float* __restrict__ xr, const float* __restrict__ mn,
    const float* __restrict__ W, const float* __restrict__ bias,
    float* __restrict__ hr, float* __restrict__ rp)
{
  const int blk = blockIdx.x;     // 0..31 (64 rows each)
  const int t = threadIdx.x;
  const int w = t >> 6, lane = t & 63;
  const int ob = w * 10;
  const bool full = (w < 3);      // last wave covers only 8 outputs
  const int b = blk * 64 + lane;

  float acc[10];
#pragma unroll
  for (int j = 0; j < 10; j++) acc[j] = 0.f;

  // genes (k = 0..127)
  const float4* xg4 = (const float4*)(xr + (size_t)b * GR);
#pragma unroll 4
  for (int k4 = 0; k4 < GR / 4; k4++) {
    float4 xv = xg4[k4];
    float xa[4] = {xv.x, xv.y, xv.z, xv.w};
#pragma unroll
    for (int j2 = 0; j2 < 4; j2++) {
      const int k = k4 * 4 + j2;
      const float2* wr = (const float2*)(W + (size_t)k * ORR + ob);
      float2 w0 = wr[0], w1 = wr[1], w2 = wr[2], w3 = wr[3];
      float2 w4 = full ? wr[4] : make_float2(0.f, 0.f);
      const float xs = xa[j2];
      acc[0]=fmaf(xs,w0.x,acc[0]); acc[1]=fmaf(xs,w0.y,acc[1]);
      acc[2]=fmaf(xs,w1.x,acc[2]); acc[3]=fmaf(xs,w1.y,acc[3]);
      acc[4]=fmaf(xs,w2.x,acc[4]); acc[5]=fmaf(xs,w2.y,acc[5]);
      acc[6]=fmaf(xs,w3.x,acc[6]); acc[7]=fmaf(xs,w3.y,acc[7]);
      acc[8]=fmaf(xs,w4.x,acc[8]); acc[9]=fmaf(xs,w4.y,acc[9]);
    }
  }
  // mid outputs (k = 128..767)
  const float4* xm4 = (const float4*)(mn + (size_t)b * (MM * OM));
#pragma unroll 4
  for (int k4 = 0; k4 < (MM * OM) / 4; k4++) {
    float4 xv = xm4[k4];
    float xa[4] = {xv.x, xv.y, xv.z, xv.w};
#pragma unroll
    for (int j2 = 0; j2 < 4; j2++) {
      const int k = GR + k4 * 4 + j2;
      const float2* wr = (const float2*)(W + (size_t)k * ORR + ob);
      float2 w0 = wr[0], w1 = wr[1], w2 = wr[2], w3 = wr[3];
      float2 w4 = full ? wr[4] : make_float2(0.f, 0.f);
      const float xs = xa[j2];
      acc[0]=fmaf(xs,w0.x,acc[0]); acc[1]=fmaf(xs,w0.y,acc[1]);
      acc[2]=fmaf(xs,w1.x,acc[2]); acc[3]=fmaf(xs,w1.y,acc[3]);
      acc[4]=fmaf(xs,w2.x,acc[4]); acc[5]=fmaf(xs,w2.y,acc[5]);
      acc[6]=fmaf(xs,w3.x,acc[6]); acc[7]=fmaf(xs,w3.y,acc[7]);
      acc[8]=fmaf(xs,w4.x,acc[8]); acc[9]=fmaf(xs,w4.y,acc[9]);
    }
  }

#pragma unroll
  for (int j = 0; j < 10; j++) {
    float bj = (j < 8 || full) ? bias[ob + j] : 0.f;
    acc[j] = tanhf(acc[j] + bj);
  }

#pragma unroll
  for (int j = 0; j < 10; j++) {
    float s1 = acc[j], s2 = acc[j] * acc[j];
#pragma unroll
    for (int d = 32; d >= 1; d >>= 1) { s1 += __shfl_xor(s1, d); s2 += __shfl_xor(s2, d); }
    if (lane == 0 && (j < 8 || full)) {
      rp[blk * 76 + ob + j] = s1;
      rp[blk * 76 + ORR + ob + j] = s2;
    }
  }
#pragma unroll
  for (int j = 0; j < 10; j++)
    if (j < 8 || full) hr[(size_t)b * ORR + ob + j] = acc[j];
}

// ---------------- root BN finalize -> output --------------------------------
__global__ __launch_bounds__(256) void k_rootnorm(
    const float* __restrict__ hr, const float* __restrict__ rp,
    const float* __restrict__ g, const float* __restrict__ be,
    float* __restrict__ out)
{
  __shared__ float sc[ORR], sh[ORR];
  const int t = threadIdx.x;
  if (t < ORR) {
    float s1 = 0.f, s2 = 0.f;
    for (int blk = 0; blk < 32; blk++) {
      s1 += rp[blk * 76 + t];
      s2 += rp[blk * 76 + ORR + t];
    }
    float mean = s1 * (1.f / BATCH);
    float var  = s2 * (1.f / BATCH) - mean * mean;
    float r = rsqrtf(var + EPSBN);
    float scv = g[t] * r;
    sc[t] = scv;
    sh[t] = be[t] - mean * scv;
  }
  __syncthreads();
  const int idx = blockIdx.x * 256 + t;   // grid sized exactly: 304*256 = 77824
  const int o = idx % ORR;
  out[idx] = hr[idx] * sc[o] + sh[o];
}

extern "C" void kernel_launch(void* const* d_in, const int* in_sizes, int n_in,
                              void* d_out, int out_size, void* d_ws, size_t ws_size,
                              hipStream_t stream) {
  (void)in_sizes; (void)n_in; (void)out_size; (void)ws_size;
  const float* x_leaf  = (const float*)d_in[0];
  const float* x_mid   = (const float*)d_in[1];
  const float* x_root  = (const float*)d_in[2];
  const float* W_leaf  = (const float*)d_in[3];
  const float* b_leaf  = (const float*)d_in[4];
  const float* g_leaf  = (const float*)d_in[5];
  const float* be_leaf = (const float*)d_in[6];
  const float* W_mid   = (const float*)d_in[7];
  const float* b_mid   = (const float*)d_in[8];
  const float* g_mid   = (const float*)d_in[9];
  const float* be_mid  = (const float*)d_in[10];
  const float* W_root  = (const float*)d_in[11];
  const float* b_root  = (const float*)d_in[12];
  const float* g_root  = (const float*)d_in[13];
  const float* be_root = (const float*)d_in[14];
  float* out = (float*)d_out;
  float* ws  = (float*)d_ws;

  float* child = ws;
  float* hm    = ws + OFF_HM;
  float* mp    = ws + OFF_MIDP;
  float* mn    = ws + OFF_MIDN;
  float* hr    = ws + OFF_HR;
  float* rp    = ws + OFF_RP;

  k_leaf<<<SS, 512, 0, stream>>>(x_leaf, W_leaf, b_leaf, g_leaf, be_leaf, child);
  k_mid<<<dim3(32, MM), 256, 0, stream>>>(x_mid, child, W_mid, b_mid, hm, mp);
  k_midnorm<<<dim3(8, MM), 256, 0, stream>>>(hm, mp, g_mid, be_mid, mn);
  k_root<<<32, 256, 0, stream>>>(x_root, mn, W_root, b_root, hr, rp);
  k_rootnorm<<<304, 256, 0, stream>>>(hr, rp, g_root, be_root, out);
}

// Round 2
// 1784.461 us; speedup vs baseline: 1.0896x; 1.0896x over previous
//
#include <hip/hip_runtime.h>
#include <hip/hip_bf16.h>

#define SS 512
#define BATCH 2048
#define GL 32
#define OL 20
#define MM 32
#define CC 16
#define GM 64
#define OM 20
#define GR 128
#define ORR 38
#define IMID 384
#define IROOT 768
#define EPSBN 1e-5f

// ---- workspace layout (floats) ----
#define SZ_CHILD ((size_t)SS * BATCH * OL)        // 20,971,520  raw leaf tanh, [s][b][20]
#define OFF_SCL  (SZ_CHILD)                       // 512*20 leaf BN scale
#define OFF_SHL  (OFF_SCL + (size_t)SS * OL)      // 512*20 leaf BN shift
#define OFF_HM   (OFF_SHL + (size_t)SS * OL)      // 32*2048*20 raw mid tanh
#define OFF_MP   (OFF_HM + (size_t)MM * BATCH * OM)  // 32*32*40 mid partial stats
#define OFF_HR   (OFF_MP + (size_t)MM * 32 * 2 * OM) // 2048*38 raw root tanh
#define OFF_RP   (OFF_HR + (size_t)BATCH * ORR)      // 32*76 root partial stats

#define FMA20(xs, wptr, acc) do { \
  const float4* _wr = (const float4*)(wptr); \
  float4 _w0=_wr[0], _w1=_wr[1], _w2=_wr[2], _w3=_wr[3], _w4=_wr[4]; \
  acc[0]=fmaf(xs,_w0.x,acc[0]);  acc[1]=fmaf(xs,_w0.y,acc[1]); \
  acc[2]=fmaf(xs,_w0.z,acc[2]);  acc[3]=fmaf(xs,_w0.w,acc[3]); \
  acc[4]=fmaf(xs,_w1.x,acc[4]);  acc[5]=fmaf(xs,_w1.y,acc[5]); \
  acc[6]=fmaf(xs,_w1.z,acc[6]);  acc[7]=fmaf(xs,_w1.w,acc[7]); \
  acc[8]=fmaf(xs,_w2.x,acc[8]);  acc[9]=fmaf(xs,_w2.y,acc[9]); \
  acc[10]=fmaf(xs,_w2.z,acc[10]); acc[11]=fmaf(xs,_w2.w,acc[11]); \
  acc[12]=fmaf(xs,_w3.x,acc[12]); acc[13]=fmaf(xs,_w3.y,acc[13]); \
  acc[14]=fmaf(xs,_w3.z,acc[14]); acc[15]=fmaf(xs,_w3.w,acc[15]); \
  acc[16]=fmaf(xs,_w4.x,acc[16]); acc[17]=fmaf(xs,_w4.y,acc[17]); \
  acc[18]=fmaf(xs,_w4.z,acc[18]); acc[19]=fmaf(xs,_w4.w,acc[19]); \
} while (0)

// ---------------- leaf: raw tanh out + in-block full-batch BN affine tables -
// Per-thread live state kept ~60 floats (sum/ssq/acc) -> no scratch spill.
__global__ __launch_bounds__(512) void k_leaf(
    const float* __restrict__ x, const float* __restrict__ W,
    const float* __restrict__ bias, const float* __restrict__ g,
    const float* __restrict__ be, float* __restrict__ child,
    float* __restrict__ scL, float* __restrict__ shL)
{
  const int s = blockIdx.x;
  const int t = threadIdx.x;
  __shared__ float Wl[GL * OL];       // 2560 B
  __shared__ float bl[OL];
  __shared__ float red[8][2 * OL];

  if (t < GL * OL / 4)
    ((float4*)Wl)[t] = ((const float4*)(W + (size_t)s * GL * OL))[t];
  else if (t >= 160 && t < 165)
    ((float4*)bl)[t - 160] = ((const float4*)(bias + s * OL))[t - 160];
  __syncthreads();

  float sum[OL], ssq[OL];
#pragma unroll
  for (int o = 0; o < OL; o++) { sum[o] = 0.f; ssq[o] = 0.f; }

#pragma unroll
  for (int rr = 0; rr < 4; rr++) {
    const int b = rr * 512 + t;
    const float4* xr = (const float4*)(x + ((size_t)s * BATCH + b) * GL);
    float acc[OL];
#pragma unroll
    for (int o = 0; o < OL; o++) acc[o] = 0.f;
#pragma unroll
    for (int i4 = 0; i4 < GL / 4; i4++) {
      float4 xv = xr[i4];
      FMA20(xv.x, &Wl[(i4 * 4 + 0) * OL], acc);
      FMA20(xv.y, &Wl[(i4 * 4 + 1) * OL], acc);
      FMA20(xv.z, &Wl[(i4 * 4 + 2) * OL], acc);
      FMA20(xv.w, &Wl[(i4 * 4 + 3) * OL], acc);
    }
    float4* dst = (float4*)(child + ((size_t)s * BATCH + b) * OL);
#pragma unroll
    for (int q = 0; q < 5; q++) {
      float4 v;
      float h0 = tanhf(acc[q*4+0] + bl[q*4+0]);
      float h1 = tanhf(acc[q*4+1] + bl[q*4+1]);
      float h2 = tanhf(acc[q*4+2] + bl[q*4+2]);
      float h3 = tanhf(acc[q*4+3] + bl[q*4+3]);
      sum[q*4+0] += h0; ssq[q*4+0] = fmaf(h0, h0, ssq[q*4+0]);
      sum[q*4+1] += h1; ssq[q*4+1] = fmaf(h1, h1, ssq[q*4+1]);
      sum[q*4+2] += h2; ssq[q*4+2] = fmaf(h2, h2, ssq[q*4+2]);
      sum[q*4+3] += h3; ssq[q*4+3] = fmaf(h3, h3, ssq[q*4+3]);
      v.x = h0; v.y = h1; v.z = h2; v.w = h3;
      dst[q] = v;
    }
  }

  const int wave = t >> 6, lane = t & 63;
#pragma unroll
  for (int o = 0; o < OL; o++) {
    float s1 = sum[o], s2 = ssq[o];
#pragma unroll
    for (int d = 32; d >= 1; d >>= 1) { s1 += __shfl_xor(s1, d); s2 += __shfl_xor(s2, d); }
    if (lane == 0) { red[wave][o] = s1; red[wave][OL + o] = s2; }
  }
  __syncthreads();
  if (t < 2 * OL) {
    float v = 0.f;
#pragma unroll
    for (int w2 = 0; w2 < 8; w2++) v += red[w2][t];
    red[0][t] = v;
  }
  __syncthreads();
  if (t < OL) {
    float mean = red[0][t] * (1.f / BATCH);
    float var  = red[0][OL + t] * (1.f / BATCH) - mean * mean;
    float rs = rsqrtf(var + EPSBN);
    float sc = g[s * OL + t] * rs;
    scL[s * OL + t] = sc;
    shL[s * OL + t] = be[s * OL + t] - mean * sc;
  }
}

// ---------------- mid: GEMM with inline leaf-BN affine; raw out + partials --
__global__ __launch_bounds__(256) void k_mid(
    const float* __restrict__ xg, const float* __restrict__ child,
    const float* __restrict__ scL, const float* __restrict__ shL,
    const float* __restrict__ W, const float* __restrict__ bias,
    float* __restrict__ hm, float* __restrict__ mp)
{
  const int chunk = blockIdx.x;   // 0..31 (64 rows each)
  const int m = blockIdx.y;       // 0..31
  const int t = threadIdx.x;
  const int kq = t >> 6;          // wave id
  const int lane = t & 63;
  const int b = chunk * 64 + lane;

  __shared__ float Wl[IMID * OM];      // 30720 B
  __shared__ float cb[3][64][21];      // 16128 B
  __shared__ float scs[CC * OL];       // 1280 B
  __shared__ float shs[CC * OL];       // 1280 B

  for (int i = t; i < IMID * OM / 4; i += 256)
    ((float4*)Wl)[i] = ((const float4*)(W + (size_t)m * IMID * OM))[i];
  if (t < 80)       ((float4*)scs)[t]      = ((const float4*)(scL + m * CC * OL))[t];
  else if (t < 160) ((float4*)shs)[t - 80] = ((const float4*)(shL + m * CC * OL))[t - 80];
  __syncthreads();

  float acc[OM];
#pragma unroll
  for (int o = 0; o < OM; o++) acc[o] = 0.f;

  // genes: wave kq handles k = kq*16 .. kq*16+15
  const float4* gx = (const float4*)(xg + ((size_t)m * BATCH + b) * GM + kq * 16);
#pragma unroll
  for (int j4 = 0; j4 < 4; j4++) {
    float4 xv = gx[j4];
    const int k = kq * 16 + j4 * 4;
    FMA20(xv.x, &Wl[(k + 0) * OM], acc);
    FMA20(xv.y, &Wl[(k + 1) * OM], acc);
    FMA20(xv.z, &Wl[(k + 2) * OM], acc);
    FMA20(xv.w, &Wl[(k + 3) * OM], acc);
  }
  // children: wave kq handles c = kq*4 .. kq*4+3
#pragma unroll
  for (int ci = 0; ci < 4; ci++) {
    const int c = kq * 4 + ci;
    const float4* cx = (const float4*)(child + ((size_t)(m * CC + c) * BATCH + b) * OL);
#pragma unroll
    for (int q = 0; q < 5; q++) {
      float4 v = cx[q];
      const int o0 = q * 4;
      const int kb = GM + c * OL;
      float x0 = fmaf(v.x, scs[c*OL+o0+0], shs[c*OL+o0+0]);
      float x1 = fmaf(v.y, scs[c*OL+o0+1], shs[c*OL+o0+1]);
      float x2 = fmaf(v.z, scs[c*OL+o0+2], shs[c*OL+o0+2]);
      float x3 = fmaf(v.w, scs[c*OL+o0+3], shs[c*OL+o0+3]);
      FMA20(x0, &Wl[(kb + o0 + 0) * OM], acc);
      FMA20(x1, &Wl[(kb + o0 + 1) * OM], acc);
      FMA20(x2, &Wl[(kb + o0 + 2) * OM], acc);
      FMA20(x3, &Wl[(kb + o0 + 3) * OM], acc);
    }
  }

  if (kq > 0) {
#pragma unroll
    for (int o = 0; o < OM; o++) cb[kq - 1][lane][o] = acc[o];
  }
  __syncthreads();

  if (kq == 0) {
#pragma unroll
    for (int o = 0; o < OM; o++) {
      float v = acc[o] + cb[0][lane][o] + cb[1][lane][o] + cb[2][lane][o] + bias[m * OM + o];
      acc[o] = tanhf(v);
    }
    float4* dst = (float4*)(hm + ((size_t)m * BATCH + b) * OM);
#pragma unroll
    for (int q = 0; q < 5; q++) {
      float4 v; v.x = acc[q*4]; v.y = acc[q*4+1]; v.z = acc[q*4+2]; v.w = acc[q*4+3];
      dst[q] = v;
    }
#pragma unroll
    for (int o = 0; o < OM; o++) {
      float s1 = acc[o], s2 = acc[o] * acc[o];
#pragma unroll
      for (int d = 32; d >= 1; d >>= 1) { s1 += __shfl_xor(s1, d); s2 += __shfl_xor(s2, d); }
      if (lane == 0) {
        mp[((size_t)m * 32 + chunk) * (2 * OM) + o] = s1;
        mp[((size_t)m * 32 + chunk) * (2 * OM) + OM + o] = s2;
      }
    }
  }
}

// ---------------- root: in-block mid-BN finalize + GEMM (W in LDS) ----------
__global__ __launch_bounds__(256) void k_root(
    const float* __restrict__ xr, const float* __restrict__ hm,
    const float* __restrict__ mp,
    const float* __restrict__ g_mid, const float* __restrict__ be_mid,
    const float* __restrict__ W, const float* __restrict__ bias,
    float* __restrict__ hr, float* __restrict__ rp)
{
  extern __shared__ float smem[];
  float* Wl  = smem;                 // 768*38 + pad = 29192 floats
  float* scm = smem + 29192;         // 640
  float* shm = smem + 29192 + 640;   // 640

  const int blk = blockIdx.x;        // 0..31 (64 rows each)
  const int t = threadIdx.x;
  const int w = t >> 6, lane = t & 63;
  const int ob = w * 10;
  const bool full = (w < 3);
  const int b = blk * 64 + lane;

  // stage W_root (116 KB) coalesced
  for (int i = t; i < (IROOT * ORR) / 2; i += 256)
    ((float2*)Wl)[i] = ((const float2*)W)[i];
  // finalize mid BN stats (32 m x 20 o)
  for (int e = t; e < MM * OM; e += 256) {
    const int m = e / OM, o = e % OM;
    float s1 = 0.f, s2 = 0.f;
    for (int c = 0; c < 32; c++) {
      s1 += mp[((size_t)m * 32 + c) * (2 * OM) + o];
      s2 += mp[((size_t)m * 32 + c) * (2 * OM) + OM + o];
    }
    float mean = s1 * (1.f / BATCH);
    float var  = s2 * (1.f / BATCH) - mean * mean;
    float r = rsqrtf(var + EPSBN);
    float sc = g_mid[e] * r;
    scm[e] = sc;
    shm[e] = be_mid[e] - mean * sc;
  }
  __syncthreads();

  float acc[10];
#pragma unroll
  for (int j = 0; j < 10; j++) acc[j] = 0.f;

#define FMA10(xs, kk) do { \
    const float2* wr = (const float2*)(Wl + (size_t)(kk) * ORR + ob); \
    float2 w0 = wr[0], w1 = wr[1], w2 = wr[2], w3 = wr[3]; \
    float2 w4 = full ? wr[4] : make_float2(0.f, 0.f); \
    acc[0]=fmaf(xs,w0.x,acc[0]); acc[1]=fmaf(xs,w0.y,acc[1]); \
    acc[2]=fmaf(xs,w1.x,acc[2]); acc[3]=fmaf(xs,w1.y,acc[3]); \
    acc[4]=fmaf(xs,w2.x,acc[4]); acc[5]=fmaf(xs,w2.y,acc[5]); \
    acc[6]=fmaf(xs,w3.x,acc[6]); acc[7]=fmaf(xs,w3.y,acc[7]); \
    acc[8]=fmaf(xs,w4.x,acc[8]); acc[9]=fmaf(xs,w4.y,acc[9]); \
  } while (0)

  // genes (k = 0..127)
  const float4* xg4 = (const float4*)(xr + (size_t)b * GR);
#pragma unroll 4
  for (int k4 = 0; k4 < GR / 4; k4++) {
    float4 xv = xg4[k4];
    FMA10(xv.x, k4 * 4 + 0);
    FMA10(xv.y, k4 * 4 + 1);
    FMA10(xv.z, k4 * 4 + 2);
    FMA10(xv.w, k4 * 4 + 3);
  }
  // mid outputs (k = 128..767), inline mid-BN affine
#pragma unroll 2
  for (int m = 0; m < MM; m++) {
    const float4* cx = (const float4*)(hm + ((size_t)m * BATCH + b) * OM);
#pragma unroll
    for (int q = 0; q < 5; q++) {
      float4 v = cx[q];
      const int o0 = q * 4;
      float x0 = fmaf(v.x, scm[m*OM+o0+0], shm[m*OM+o0+0]);
      float x1 = fmaf(v.y, scm[m*OM+o0+1], shm[m*OM+o0+1]);
      float x2 = fmaf(v.z, scm[m*OM+o0+2], shm[m*OM+o0+2]);
      float x3 = fmaf(v.w, scm[m*OM+o0+3], shm[m*OM+o0+3]);
      FMA10(x0, GR + m * OM + o0 + 0);
      FMA10(x1, GR + m * OM + o0 + 1);
      FMA10(x2, GR + m * OM + o0 + 2);
      FMA10(x3, GR + m * OM + o0 + 3);
    }
  }
#undef FMA10

#pragma unroll
  for (int j = 0; j < 10; j++) {
    float bj = (j < 8 || full) ? bias[ob + j] : 0.f;
    acc[j] = tanhf(acc[j] + bj);
  }

#pragma unroll
  for (int j = 0; j < 10; j++) {
    float s1 = acc[j], s2 = acc[j] * acc[j];
#pragma unroll
    for (int d = 32; d >= 1; d >>= 1) { s1 += __shfl_xor(s1, d); s2 += __shfl_xor(s2, d); }
    if (lane == 0 && (j < 8 || full)) {
      rp[blk * 76 + ob + j] = s1;
      rp[blk * 76 + ORR + ob + j] = s2;
    }
  }
#pragma unroll
  for (int j = 0; j < 10; j++)
    if (j < 8 || full) hr[(size_t)b * ORR + ob + j] = acc[j];
}

// ---------------- root BN finalize -> output --------------------------------
__global__ __launch_bounds__(256) void k_rootnorm(
    const float* __restrict__ hr, const float* __restrict__ rp,
    const float* __restrict__ g, const float* __restrict__ be,
    float* __restrict__ out)
{
  __shared__ float sc[ORR], sh[ORR];
  const int t = threadIdx.x;
  if (t < ORR) {
    float s1 = 0.f, s2 = 0.f;
    for (int blk = 0; blk < 32; blk++) {
      s1 += rp[blk * 76 + t];
      s2 += rp[blk * 76 + ORR + t];
    }
    float mean = s1 * (1.f / BATCH);
    float var  = s2 * (1.f / BATCH) - mean * mean;
    float r = rsqrtf(var + EPSBN);
    float scv = g[t] * r;
    sc[t] = scv;
    sh[t] = be[t] - mean * scv;
  }
  __syncthreads();
  const int idx = blockIdx.x * 256 + t;   // 304*256 = 77824 exactly
  const int o = idx % ORR;
  out[idx] = hr[idx] * sc[o] + sh[o];
}

extern "C" void kernel_launch(void* const* d_in, const int* in_sizes, int n_in,
                              void* d_out, int out_size, void* d_ws, size_t ws_size,
                              hipStream_t stream) {
  (void)in_sizes; (void)n_in; (void)out_size; (void)ws_size;
  const float* x_leaf  = (const float*)d_in[0];
  const float* x_mid   = (const float*)d_in[1];
  const float* x_root  = (const float*)d_in[2];
  const float* W_leaf  = (const float*)d_in[3];
  const float* b_leaf  = (const float*)d_in[4];
  const float* g_leaf  = (const float*)d_in[5];
  const float* be_leaf = (const float*)d_in[6];
  const float* W_mid   = (const float*)d_in[7];
  const float* b_mid   = (const float*)d_in[8];
  const float* g_mid   = (const float*)d_in[9];
  const float* be_mid  = (const float*)d_in[10];
  const float* W_root  = (const float*)d_in[11];
  const float* b_root  = (const float*)d_in[12];
  const float* g_root  = (const float*)d_in[13];
  const float* be_root = (const float*)d_in[14];
  float* out = (float*)d_out;
  float* ws  = (float*)d_ws;

  float* child = ws;
  float* scL   = ws + OFF_SCL;
  float* shL   = ws + OFF_SHL;
  float* hm    = ws + OFF_HM;
  float* mp    = ws + OFF_MP;
  float* hr    = ws + OFF_HR;
  float* rp    = ws + OFF_RP;

  k_leaf<<<SS, 512, 0, stream>>>(x_leaf, W_leaf, b_leaf, g_leaf, be_leaf,
                                 child, scL, shL);
  k_mid<<<dim3(32, MM), 256, 0, stream>>>(x_mid, child, scL, shL, W_mid, b_mid,
                                          hm, mp);
  const size_t root_lds = (29192 + 640 + 640) * sizeof(float);
  k_root<<<32, 256, root_lds, stream>>>(x_root, hm, mp, g_mid, be_mid,
                                        W_root, b_root, hr, rp);
  k_rootnorm<<<304, 256, 0, stream>>>(hr, rp, g_root, be_root, out);
}

// Round 3
// 1582.245 us; speedup vs baseline: 1.2288x; 1.1278x over previous
//
#include <hip/hip_runtime.h>
#include <hip/hip_bf16.h>

#define SS 512
#define BATCH 2048
#define GL 32
#define OL 20
#define MM 32
#define CC 16
#define GM 64
#define OM 20
#define GR 128
#define ORR 38
#define IMID 384
#define IROOT 768
#define EPSBN 1e-5f

// ---- workspace layout (floats) ----
#define SZ_CHILD ((size_t)SS * BATCH * OL)        // raw leaf tanh, [s][b][20]
#define OFF_SCL  (SZ_CHILD)
#define OFF_SHL  (OFF_SCL + (size_t)SS * OL)
#define OFF_HM   (OFF_SHL + (size_t)SS * OL)
#define OFF_MP   (OFF_HM + (size_t)MM * BATCH * OM)
#define OFF_HR   (OFF_MP + (size_t)MM * 32 * 2 * OM)
#define OFF_RP   (OFF_HR + (size_t)BATCH * ORR)

#define FMA20(xs, wptr, acc) do { \
  const float4* _wr = (const float4*)(wptr); \
  float4 _w0=_wr[0], _w1=_wr[1], _w2=_wr[2], _w3=_wr[3], _w4=_wr[4]; \
  acc[0]=fmaf(xs,_w0.x,acc[0]);  acc[1]=fmaf(xs,_w0.y,acc[1]); \
  acc[2]=fmaf(xs,_w0.z,acc[2]);  acc[3]=fmaf(xs,_w0.w,acc[3]); \
  acc[4]=fmaf(xs,_w1.x,acc[4]);  acc[5]=fmaf(xs,_w1.y,acc[5]); \
  acc[6]=fmaf(xs,_w1.z,acc[6]);  acc[7]=fmaf(xs,_w1.w,acc[7]); \
  acc[8]=fmaf(xs,_w2.x,acc[8]);  acc[9]=fmaf(xs,_w2.y,acc[9]); \
  acc[10]=fmaf(xs,_w2.z,acc[10]); acc[11]=fmaf(xs,_w2.w,acc[11]); \
  acc[12]=fmaf(xs,_w3.x,acc[12]); acc[13]=fmaf(xs,_w3.y,acc[13]); \
  acc[14]=fmaf(xs,_w3.z,acc[14]); acc[15]=fmaf(xs,_w3.w,acc[15]); \
  acc[16]=fmaf(xs,_w4.x,acc[16]); acc[17]=fmaf(xs,_w4.y,acc[17]); \
  acc[18]=fmaf(xs,_w4.z,acc[18]); acc[19]=fmaf(xs,_w4.w,acc[19]); \
} while (0)

// ---------------- leaf: raw tanh out + in-block full-batch BN affine tables -
// unroll 1 on the row loop: keep only ONE iteration's loads in flight so the
// compiler cannot hoist 4x8 float4 loads and spill the accumulators.
__global__ __launch_bounds__(512, 2) void k_leaf(
    const float* __restrict__ x, const float* __restrict__ W,
    const float* __restrict__ bias, const float* __restrict__ g,
    const float* __restrict__ be, float* __restrict__ child,
    float* __restrict__ scL, float* __restrict__ shL)
{
  const int s = blockIdx.x;
  const int t = threadIdx.x;
  __shared__ float Wl[GL * OL];       // 2560 B
  __shared__ float bl[OL];
  __shared__ float red[8][2 * OL];

  if (t < GL * OL / 4)
    ((float4*)Wl)[t] = ((const float4*)(W + (size_t)s * GL * OL))[t];
  else if (t >= 160 && t < 165)
    ((float4*)bl)[t - 160] = ((const float4*)(bias + s * OL))[t - 160];
  __syncthreads();

  float sum[OL], ssq[OL];
#pragma unroll
  for (int o = 0; o < OL; o++) { sum[o] = 0.f; ssq[o] = 0.f; }

#pragma unroll 1
  for (int rr = 0; rr < 4; rr++) {
    const int b = rr * 512 + t;
    const float4* xr = (const float4*)(x + ((size_t)s * BATCH + b) * GL);
    float acc[OL];
#pragma unroll
    for (int o = 0; o < OL; o++) acc[o] = 0.f;
#pragma unroll
    for (int i4 = 0; i4 < GL / 4; i4++) {
      float4 xv = xr[i4];
      FMA20(xv.x, &Wl[(i4 * 4 + 0) * OL], acc);
      FMA20(xv.y, &Wl[(i4 * 4 + 1) * OL], acc);
      FMA20(xv.z, &Wl[(i4 * 4 + 2) * OL], acc);
      FMA20(xv.w, &Wl[(i4 * 4 + 3) * OL], acc);
    }
    float4* dst = (float4*)(child + ((size_t)s * BATCH + b) * OL);
#pragma unroll
    for (int q = 0; q < 5; q++) {
      float4 v;
      float h0 = tanhf(acc[q*4+0] + bl[q*4+0]);
      float h1 = tanhf(acc[q*4+1] + bl[q*4+1]);
      float h2 = tanhf(acc[q*4+2] + bl[q*4+2]);
      float h3 = tanhf(acc[q*4+3] + bl[q*4+3]);
      sum[q*4+0] += h0; ssq[q*4+0] = fmaf(h0, h0, ssq[q*4+0]);
      sum[q*4+1] += h1; ssq[q*4+1] = fmaf(h1, h1, ssq[q*4+1]);
      sum[q*4+2] += h2; ssq[q*4+2] = fmaf(h2, h2, ssq[q*4+2]);
      sum[q*4+3] += h3; ssq[q*4+3] = fmaf(h3, h3, ssq[q*4+3]);
      v.x = h0; v.y = h1; v.z = h2; v.w = h3;
      dst[q] = v;
    }
  }

  const int wave = t >> 6, lane = t & 63;
#pragma unroll
  for (int o = 0; o < OL; o++) {
    float s1 = sum[o], s2 = ssq[o];
#pragma unroll
    for (int d = 32; d >= 1; d >>= 1) { s1 += __shfl_xor(s1, d); s2 += __shfl_xor(s2, d); }
    if (lane == 0) { red[wave][o] = s1; red[wave][OL + o] = s2; }
  }
  __syncthreads();
  if (t < 2 * OL) {
    float v = 0.f;
#pragma unroll
    for (int w2 = 0; w2 < 8; w2++) v += red[w2][t];
    red[0][t] = v;
  }
  __syncthreads();
  if (t < OL) {
    float mean = red[0][t] * (1.f / BATCH);
    float var  = red[0][OL + t] * (1.f / BATCH) - mean * mean;
    float rs = rsqrtf(var + EPSBN);
    float sc = g[s * OL + t] * rs;
    scL[s * OL + t] = sc;
    shL[s * OL + t] = be[s * OL + t] - mean * sc;
  }
}

// ---------------- mid: GEMM with inline leaf-BN affine; raw out + partials --
__global__ __launch_bounds__(256, 2) void k_mid(
    const float* __restrict__ xg, const float* __restrict__ child,
    const float* __restrict__ scL, const float* __restrict__ shL,
    const float* __restrict__ W, const float* __restrict__ bias,
    float* __restrict__ hm, float* __restrict__ mp)
{
  const int chunk = blockIdx.x;   // 0..31 (64 rows each)
  const int m = blockIdx.y;       // 0..31
  const int t = threadIdx.x;
  const int kq = t >> 6;          // wave id
  const int lane = t & 63;
  const int b = chunk * 64 + lane;

  __shared__ float Wl[IMID * OM];      // 30720 B
  __shared__ float cb[3][64][21];      // 16128 B
  __shared__ float scs[CC * OL];       // 1280 B
  __shared__ float shs[CC * OL];       // 1280 B

  for (int i = t; i < IMID * OM / 4; i += 256)
    ((float4*)Wl)[i] = ((const float4*)(W + (size_t)m * IMID * OM))[i];
  if (t < 80)       ((float4*)scs)[t]      = ((const float4*)(scL + m * CC * OL))[t];
  else if (t < 160) ((float4*)shs)[t - 80] = ((const float4*)(shL + m * CC * OL))[t - 80];
  __syncthreads();

  float acc[OM];
#pragma unroll
  for (int o = 0; o < OM; o++) acc[o] = 0.f;

  // genes: wave kq handles k = kq*16 .. kq*16+15
  const float4* gx = (const float4*)(xg + ((size_t)m * BATCH + b) * GM + kq * 16);
#pragma unroll 1
  for (int j4 = 0; j4 < 4; j4++) {
    float4 xv = gx[j4];
    const int k = kq * 16 + j4 * 4;
    FMA20(xv.x, &Wl[(k + 0) * OM], acc);
    FMA20(xv.y, &Wl[(k + 1) * OM], acc);
    FMA20(xv.z, &Wl[(k + 2) * OM], acc);
    FMA20(xv.w, &Wl[(k + 3) * OM], acc);
  }
  // children: wave kq handles c = kq*4 .. kq*4+3; unroll 1 -> no load hoisting
#pragma unroll 1
  for (int ci = 0; ci < 4; ci++) {
    const int c = kq * 4 + ci;
    const float4* cx = (const float4*)(child + ((size_t)(m * CC + c) * BATCH + b) * OL);
#pragma unroll
    for (int q = 0; q < 5; q++) {
      float4 v = cx[q];
      const int o0 = q * 4;
      const int kb = GM + c * OL;
      float x0 = fmaf(v.x, scs[c*OL+o0+0], shs[c*OL+o0+0]);
      float x1 = fmaf(v.y, scs[c*OL+o0+1], shs[c*OL+o0+1]);
      float x2 = fmaf(v.z, scs[c*OL+o0+2], shs[c*OL+o0+2]);
      float x3 = fmaf(v.w, scs[c*OL+o0+3], shs[c*OL+o0+3]);
      FMA20(x0, &Wl[(kb + o0 + 0) * OM], acc);
      FMA20(x1, &Wl[(kb + o0 + 1) * OM], acc);
      FMA20(x2, &Wl[(kb + o0 + 2) * OM], acc);
      FMA20(x3, &Wl[(kb + o0 + 3) * OM], acc);
    }
  }

  if (kq > 0) {
#pragma unroll
    for (int o = 0; o < OM; o++) cb[kq - 1][lane][o] = acc[o];
  }
  __syncthreads();

  if (kq == 0) {
#pragma unroll
    for (int o = 0; o < OM; o++) {
      float v = acc[o] + cb[0][lane][o] + cb[1][lane][o] + cb[2][lane][o] + bias[m * OM + o];
      acc[o] = tanhf(v);
    }
    float4* dst = (float4*)(hm + ((size_t)m * BATCH + b) * OM);
#pragma unroll
    for (int q = 0; q < 5; q++) {
      float4 v; v.x = acc[q*4]; v.y = acc[q*4+1]; v.z = acc[q*4+2]; v.w = acc[q*4+3];
      dst[q] = v;
    }
#pragma unroll
    for (int o = 0; o < OM; o++) {
      float s1 = acc[o], s2 = acc[o] * acc[o];
#pragma unroll
      for (int d = 32; d >= 1; d >>= 1) { s1 += __shfl_xor(s1, d); s2 += __shfl_xor(s2, d); }
      if (lane == 0) {
        mp[((size_t)m * 32 + chunk) * (2 * OM) + o] = s1;
        mp[((size_t)m * 32 + chunk) * (2 * OM) + OM + o] = s2;
      }
    }
  }
}

// ---------------- root: in-block mid-BN finalize + GEMM (W in LDS) ----------
__global__ __launch_bounds__(256, 2) void k_root(
    const float* __restrict__ xr, const float* __restrict__ hm,
    const float* __restrict__ mp,
    const float* __restrict__ g_mid, const float* __restrict__ be_mid,
    const float* __restrict__ W, const float* __restrict__ bias,
    float* __restrict__ hr, float* __restrict__ rp)
{
  extern __shared__ float smem[];
  float* Wl  = smem;                 // 768*38 = 29184 (+pad) floats
  float* scm = smem + 29192;         // 640
  float* shm = smem + 29192 + 640;   // 640

  const int blk = blockIdx.x;        // 0..31 (64 rows each)
  const int t = threadIdx.x;
  const int w = t >> 6, lane = t & 63;
  const int ob = w * 10;
  const bool full = (w < 3);
  const int b = blk * 64 + lane;

  for (int i = t; i < (IROOT * ORR) / 2; i += 256)
    ((float2*)Wl)[i] = ((const float2*)W)[i];
  for (int e = t; e < MM * OM; e += 256) {
    const int m = e / OM, o = e % OM;
    float s1 = 0.f, s2 = 0.f;
    for (int c = 0; c < 32; c++) {
      s1 += mp[((size_t)m * 32 + c) * (2 * OM) + o];
      s2 += mp[((size_t)m * 32 + c) * (2 * OM) + OM + o];
    }
    float mean = s1 * (1.f / BATCH);
    float var  = s2 * (1.f / BATCH) - mean * mean;
    float r = rsqrtf(var + EPSBN);
    float sc = g_mid[e] * r;
    scm[e] = sc;
    shm[e] = be_mid[e] - mean * sc;
  }
  __syncthreads();

  float acc[10];
#pragma unroll
  for (int j = 0; j < 10; j++) acc[j] = 0.f;

#define FMA10(xs, kk) do { \
    const float2* wr = (const float2*)(Wl + (size_t)(kk) * ORR + ob); \
    float2 w0 = wr[0], w1 = wr[1], w2 = wr[2], w3 = wr[3]; \
    float2 w4 = full ? wr[4] : make_float2(0.f, 0.f); \
    acc[0]=fmaf(xs,w0.x,acc[0]); acc[1]=fmaf(xs,w0.y,acc[1]); \
    acc[2]=fmaf(xs,w1.x,acc[2]); acc[3]=fmaf(xs,w1.y,acc[3]); \
    acc[4]=fmaf(xs,w2.x,acc[4]); acc[5]=fmaf(xs,w2.y,acc[5]); \
    acc[6]=fmaf(xs,w3.x,acc[6]); acc[7]=fmaf(xs,w3.y,acc[7]); \
    acc[8]=fmaf(xs,w4.x,acc[8]); acc[9]=fmaf(xs,w4.y,acc[9]); \
  } while (0)

  // genes (k = 0..127)
  const float4* xg4 = (const float4*)(xr + (size_t)b * GR);
#pragma unroll 1
  for (int k4 = 0; k4 < GR / 4; k4++) {
    float4 xv = xg4[k4];
    FMA10(xv.x, k4 * 4 + 0);
    FMA10(xv.y, k4 * 4 + 1);
    FMA10(xv.z, k4 * 4 + 2);
    FMA10(xv.w, k4 * 4 + 3);
  }
  // mid outputs (k = 128..767), inline mid-BN affine
#pragma unroll 1
  for (int m = 0; m < MM; m++) {
    const float4* cx = (const float4*)(hm + ((size_t)m * BATCH + b) * OM);
#pragma unroll
    for (int q = 0; q < 5; q++) {
      float4 v = cx[q];
      const int o0 = q * 4;
      float x0 = fmaf(v.x, scm[m*OM+o0+0], shm[m*OM+o0+0]);
      float x1 = fmaf(v.y, scm[m*OM+o0+1], shm[m*OM+o0+1]);
      float x2 = fmaf(v.z, scm[m*OM+o0+2], shm[m*OM+o0+2]);
      float x3 = fmaf(v.w, scm[m*OM+o0+3], shm[m*OM+o0+3]);
      FMA10(x0, GR + m * OM + o0 + 0);
      FMA10(x1, GR + m * OM + o0 + 1);
      FMA10(x2, GR + m * OM + o0 + 2);
      FMA10(x3, GR + m * OM + o0 + 3);
    }
  }
#undef FMA10

#pragma unroll
  for (int j = 0; j < 10; j++) {
    float bj = (j < 8 || full) ? bias[ob + j] : 0.f;
    acc[j] = tanhf(acc[j] + bj);
  }

#pragma unroll
  for (int j = 0; j < 10; j++) {
    float s1 = acc[j], s2 = acc[j] * acc[j];
#pragma unroll
    for (int d = 32; d >= 1; d >>= 1) { s1 += __shfl_xor(s1, d); s2 += __shfl_xor(s2, d); }
    if (lane == 0 && (j < 8 || full)) {
      rp[blk * 76 + ob + j] = s1;
      rp[blk * 76 + ORR + ob + j] = s2;
    }
  }
#pragma unroll
  for (int j = 0; j < 10; j++)
    if (j < 8 || full) hr[(size_t)b * ORR + ob + j] = acc[j];
}

// ---------------- root BN finalize -> output --------------------------------
__global__ __launch_bounds__(256) void k_rootnorm(
    const float* __restrict__ hr, const float* __restrict__ rp,
    const float* __restrict__ g, const float* __restrict__ be,
    float* __restrict__ out)
{
  __shared__ float sc[ORR], sh[ORR];
  const int t = threadIdx.x;
  if (t < ORR) {
    float s1 = 0.f, s2 = 0.f;
    for (int blk = 0; blk < 32; blk++) {
      s1 += rp[blk * 76 + t];
      s2 += rp[blk * 76 + ORR + t];
    }
    float mean = s1 * (1.f / BATCH);
    float var  = s2 * (1.f / BATCH) - mean * mean;
    float r = rsqrtf(var + EPSBN);
    float scv = g[t] * r;
    sc[t] = scv;
    sh[t] = be[t] - mean * scv;
  }
  __syncthreads();
  const int idx = blockIdx.x * 256 + t;   // 304*256 = 77824 exactly
  const int o = idx % ORR;
  out[idx] = hr[idx] * sc[o] + sh[o];
}

extern "C" void kernel_launch(void* const* d_in, const int* in_sizes, int n_in,
                              void* d_out, int out_size, void* d_ws, size_t ws_size,
                              hipStream_t stream) {
  (void)in_sizes; (void)n_in; (void)out_size; (void)ws_size;
  const float* x_leaf  = (const float*)d_in[0];
  const float* x_mid   = (const float*)d_in[1];
  const float* x_root  = (const float*)d_in[2];
  const float* W_leaf  = (const float*)d_in[3];
  const float* b_leaf  = (const float*)d_in[4];
  const float* g_leaf  = (const float*)d_in[5];
  const float* be_leaf = (const float*)d_in[6];
  const float* W_mid   = (const float*)d_in[7];
  const float* b_mid   = (const float*)d_in[8];
  const float* g_mid   = (const float*)d_in[9];
  const float* be_mid  = (const float*)d_in[10];
  const float* W_root  = (const float*)d_in[11];
  const float* b_root  = (const float*)d_in[12];
  const float* g_root  = (const float*)d_in[13];
  const float* be_root = (const float*)d_in[14];
  float* out = (float*)d_out;
  float* ws  = (float*)d_ws;

  float* child = ws;
  float* scL   = ws + OFF_SCL;
  float* shL   = ws + OFF_SHL;
  float* hm    = ws + OFF_HM;
  float* mp    = ws + OFF_MP;
  float* hr    = ws + OFF_HR;
  float* rp    = ws + OFF_RP;

  k_leaf<<<SS, 512, 0, stream>>>(x_leaf, W_leaf, b_leaf, g_leaf, be_leaf,
                                 child, scL, shL);
  k_mid<<<dim3(32, MM), 256, 0, stream>>>(x_mid, child, scL, shL, W_mid, b_mid,
                                          hm, mp);
  const size_t root_lds = (29192 + 640 + 640) * sizeof(float);
  k_root<<<32, 256, root_lds, stream>>>(x_root, hm, mp, g_mid, be_mid,
                                        W_root, b_root, hr, rp);
  k_rootnorm<<<304, 256, 0, stream>>>(hr, rp, g_root, be_root, out);
}